// Round 1
// 539.756 us; speedup vs baseline: 1.1382x; 1.1382x over previous
//
#include <hip/hip_runtime.h>

typedef _Float16 f16x8 __attribute__((ext_vector_type(8)));
typedef float    f32x4 __attribute__((ext_vector_type(4)));

#define NROWS   262144
#define DIN     128
#define DOUT    256
#define NCHUNKS (NROWS / 64)          // 4096 blocks, 64 rows each (4 waves x 16)
#define WS_NEED (DIN * DOUT * 2 + DOUT * 4)   // W' fp16 + b2 table

#define SWZ_F(x, pat) __int_as_float(__builtin_amdgcn_ds_swizzle(__float_as_int(x), (pat)))
#define SWZ_I(x, pat) __builtin_amdgcn_ds_swizzle((x), (pat))

// DPP cross-lane ops (VALU pipe, ~4cyc)
template<int CTRL>
__device__ __forceinline__ float dpp_addf(float x) {
    const int y = __builtin_amdgcn_mov_dpp(__float_as_int(x), CTRL, 0xF, 0xF, true);
    return x + __int_as_float(y);
}
template<int CTRL>
__device__ __forceinline__ float dpp_maxf(float x) {
    const int y = __builtin_amdgcn_mov_dpp(__float_as_int(x), CTRL, 0xF, 0xF, true);
    return fmaxf(x, __int_as_float(y));
}
#define DPP_XOR1 0xB1   // quad_perm [1,0,3,2]
#define DPP_XOR2 0x4E   // quad_perm [2,3,0,1]
#define DPP_HMIR 0x141  // row_half_mirror: swaps quads within 8-lane group

// ---------- prep: W' = W * gamma/rsqrt(var+eps) in fp16 B-frag order; b2 table ----------
__global__ void prep_kernel(const float* __restrict__ W,
                            const float* __restrict__ gamma,
                            const float* __restrict__ beta,
                            const float* __restrict__ mmean,
                            const float* __restrict__ mvar,
                            _Float16* __restrict__ wq,
                            float* __restrict__ b2tab)
{
    const int tid  = blockIdx.x * 256 + threadIdx.x;    // 0..4095 = (t, q, lane)
    const int t    = tid >> 8;
    const int q    = (tid >> 6) & 3;
    const int lane = tid & 63;
    const int n    = 16 * t + (lane & 15);
    const int k0   = 32 * q + 8 * (lane >> 4);
    const float inv = gamma[n] / sqrtf(mvar[n] + 1e-3f);
    f16x8 v;
    #pragma unroll
    for (int j = 0; j < 8; ++j)
        v[j] = (_Float16)(W[(k0 + j) * DOUT + n] * inv);
    *(f16x8*)(wq + (size_t)tid * 8) = v;               // frag half-index = ((t*4+q)*64+lane)*8+j
    if (blockIdx.x == 0) {
        const int c = threadIdx.x;
        const float invc = gamma[c] / sqrtf(mvar[c] + 1e-3f);
        b2tab[c] = beta[c] - mmean[c] * invc;
    }
}

// Michelot fixed point with warm start tau0 = rowmax - 1.
// Valid: sparsemax probs sum to 1 and are >=0, so p_max = max - tau* <= 1
// => tau* >= max - 1, and Michelot from any tau0 <= tau* is monotone
// non-decreasing with monotonically shrinking support => exact same fixed
// point, just fewer (and cheaper, smaller-support) iterations.
// zt = 8 x f32x4 (32 cols of one row per lane), row shared by the 8 lanes
// with equal (lane>>3). DPP tree-reduce over those 8.
__device__ __forceinline__ float michelot_ws(const f32x4* zt, float tau0) {
    float tau = tau0, kprev = 0.0f;     // K >= 1 always (max in support), so 0 never matches
    for (int it = 0; it < 64; ++it) {
        float S = 0.0f, K = 0.0f;
        #pragma unroll
        for (int c = 0; c < 8; ++c) {
            #pragma unroll
            for (int j = 0; j < 4; ++j) {
                const float z = zt[c][j];
                const bool b = z > tau;
                S += b ? z : 0.0f;
                K += b ? 1.0f : 0.0f;
            }
        }
        S = dpp_addf<DPP_XOR1>(S); K = dpp_addf<DPP_XOR1>(K);
        S = dpp_addf<DPP_XOR2>(S); K = dpp_addf<DPP_XOR2>(K);
        S = dpp_addf<DPP_HMIR>(S); K = dpp_addf<DPP_HMIR>(K);
        tau = (S - 1.0f) * __builtin_amdgcn_rcpf(K);
        const bool conv = (K == kprev);
        kprev = K;
        if (__all(conv)) break;
    }
    return tau;
}

// ---------- main: GEMM(fp16 MFMA) -> per-wave LDS transpose (no barriers) ----------
// Register-pressure discipline (the round-0 kernel spilled ~32 VGPRs -> +225MB
// scratch writes): never have acc(64) + more than one 32-reg streaming buffer
// live at once. pv0 is issued only after the pass-1 LDS writes kill acc;
// pv1 is issued after BN0 frees pv0 (overlapping michelot-0).
__global__ __launch_bounds__(256, 4)
void attentive_main(const float* __restrict__ A,
                    const float* __restrict__ priors,
                    const _Float16* __restrict__ wq,
                    const float* __restrict__ b2tab,
                    float* __restrict__ out)
{
    __shared__ float tbuf[4][8 * 256];     // 8 KiB per wave, XOR-swizzled

    const int tid  = threadIdx.x;
    const int lane = tid & 63;
    const int wv   = tid >> 6;
    const int nl   = lane & 15;            // MFMA C-layout col-low / A row
    const int quad = lane >> 4;
    const int lo   = lane & 7;             // epilogue: col-group
    const int hi   = lane >> 3;            // epilogue: row within 8-row pass
    const int r0   = blockIdx.x * 64 + wv * 16;
    const int cb   = lo << 2;              // 16B offset within each 128B col-group

    // ---- A fragments: A[m=nl][k = 32q + 8*quad + j], fp32 -> fp16 ----
    f16x8 af[4];
    {
        const float* arow = A + (size_t)(r0 + nl) * DIN + (quad << 3);
        #pragma unroll
        for (int q = 0; q < 4; ++q) {
            const f32x4 vlo = *(const f32x4*)(arow + (q << 5));
            const f32x4 vhi = *(const f32x4*)(arow + (q << 5) + 4);
            f16x8 v;
            v[0] = (_Float16)vlo[0]; v[1] = (_Float16)vlo[1];
            v[2] = (_Float16)vlo[2]; v[3] = (_Float16)vlo[3];
            v[4] = (_Float16)vhi[0]; v[5] = (_Float16)vhi[1];
            v[6] = (_Float16)vhi[2]; v[7] = (_Float16)vhi[3];
            af[q] = v;
        }
    }

    // ---- GEMM: acc = A @ W'  (C-layout: col=16t+nl, row=4*quad+j) ----
    f32x4 acc[16];
    #pragma unroll
    for (int t = 0; t < 16; ++t) {
        f32x4 c = {0.f, 0.f, 0.f, 0.f};
        #pragma unroll
        for (int q = 0; q < 4; ++q) {
            const f16x8 bf = *(const f16x8*)(wq + ((size_t)((t << 2) + q) * 64 + lane) * 8);
            c = __builtin_amdgcn_mfma_f32_16x16x32_f16(af[q], bf, c, 0, 0, 0);
        }
        acc[t] = c;
    }

    float* buf = &tbuf[wv][0];

    // ---- pass-0 LDS writes: rows 0..7 (lanes quad 0,1) ----
    if (quad < 2) {
        #pragma unroll
        for (int t = 0; t < 16; ++t) {
            const int col = (t << 4) + nl;
            const int g = col >> 2, off = col & 3;
            #pragma unroll
            for (int j = 0; j < 4; ++j) {
                const int br = ((quad & 1) << 2) + j;
                buf[br * 256 + ((g ^ br) << 2) + off] = acc[t][j];
            }
        }
    }
    __asm__ volatile("s_waitcnt lgkmcnt(0)" ::: "memory");   // wave-internal: writes drained

    // ---- pass-0 LDS reads ----                       [live: acc(64)+zt0(32)]
    f32x4 zt0[8];
    #pragma unroll
    for (int c = 0; c < 8; ++c) {
        const int gp = ((c << 3) + lo) ^ hi;
        zt0[c] = *(const f32x4*)&buf[hi * 256 + (gp << 2)];
    }
    __asm__ volatile("s_waitcnt lgkmcnt(0)" ::: "memory");   // zt0 materialized (WAR safe)

    // ---- pass-1 LDS writes: rows 8..15 (lanes quad 2,3); acc dies here ----
    if (quad >= 2) {
        #pragma unroll
        for (int t = 0; t < 16; ++t) {
            const int col = (t << 4) + nl;
            const int g = col >> 2, off = col & 3;
            #pragma unroll
            for (int j = 0; j < 4; ++j) {
                const int br = ((quad & 1) << 2) + j;
                buf[br * 256 + ((g ^ br) << 2) + off] = acc[t][j];
            }
        }
    }

    // ---- pass-0 priors loads (acc dead -> pressure headroom) ----
    f32x4 pv0[8];
    {
        const float* pr = priors + (size_t)(r0 + hi) * DOUT;
        #pragma unroll
        for (int c = 0; c < 8; ++c)
            pv0[c] = __builtin_nontemporal_load((const f32x4*)(pr + (c << 5) + cb));
    }

    // ---- pass-0 epilogue: BN + prior + row max ----
    {
        float m = -3.0e38f;
        #pragma unroll
        for (int c = 0; c < 8; ++c) {
            const f32x4 b2 = *(const f32x4*)(b2tab + (c << 5) + cb);
            #pragma unroll
            for (int j = 0; j < 4; ++j) {
                const float z = (zt0[c][j] + b2[j]) * pv0[c][j];
                zt0[c][j] = z;
                m = fmaxf(m, z);
            }
        }
        m = dpp_maxf<DPP_XOR1>(m);
        m = dpp_maxf<DPP_XOR2>(m);
        m = dpp_maxf<DPP_HMIR>(m);

        // ---- issue pass-1 priors loads (pv0 dead; overlap with michelot-0) ----
        f32x4 pv1[8];
        {
            const float* pr = priors + (size_t)(r0 + 8 + hi) * DOUT;
            #pragma unroll
            for (int c = 0; c < 8; ++c)
                pv1[c] = __builtin_nontemporal_load((const f32x4*)(pr + (c << 5) + cb));
        }

        const float tau = michelot_ws(zt0, m - 1.0f);
        const int rg = r0 + hi;
        #pragma unroll
        for (int c = 0; c < 8; ++c) {
            f32x4 o;
            #pragma unroll
            for (int j = 0; j < 4; ++j)
                o[j] = fmaxf(zt0[c][j] - tau, 0.0f);
            __builtin_nontemporal_store(o, (f32x4*)(out + (size_t)rg * DOUT + (c << 5) + cb));
        }

        __asm__ volatile("s_waitcnt lgkmcnt(0)" ::: "memory");   // pass-1 writes drained

        // ---- pass-1 reads + epilogue ----
        f32x4 zt1[8];
        #pragma unroll
        for (int c = 0; c < 8; ++c) {
            const int gp = ((c << 3) + lo) ^ hi;
            zt1[c] = *(const f32x4*)&buf[hi * 256 + (gp << 2)];
        }
        float m1 = -3.0e38f;
        #pragma unroll
        for (int c = 0; c < 8; ++c) {
            const f32x4 b2 = *(const f32x4*)(b2tab + (c << 5) + cb);
            #pragma unroll
            for (int j = 0; j < 4; ++j) {
                const float z = (zt1[c][j] + b2[j]) * pv1[c][j];
                zt1[c][j] = z;
                m1 = fmaxf(m1, z);
            }
        }
        m1 = dpp_maxf<DPP_XOR1>(m1);
        m1 = dpp_maxf<DPP_XOR2>(m1);
        m1 = dpp_maxf<DPP_HMIR>(m1);

        const float tau1 = michelot_ws(zt1, m1 - 1.0f);
        const int rg1 = r0 + 8 + hi;
        #pragma unroll
        for (int c = 0; c < 8; ++c) {
            f32x4 o;
            #pragma unroll
            for (int j = 0; j < 4; ++j)
                o[j] = fmaxf(zt1[c][j] - tau1, 0.0f);
            __builtin_nontemporal_store(o, (f32x4*)(out + (size_t)rg1 * DOUT + (c << 5) + cb));
        }
    }
}

// ---------- fallback (round-1 kernel, proven correct) for tiny ws ----------
__global__ __launch_bounds__(256, 2)
void attentive_fallback(const float* __restrict__ A,
                        const float* __restrict__ priors,
                        const float* __restrict__ W,
                        const float* __restrict__ gamma,
                        const float* __restrict__ beta,
                        const float* __restrict__ mmean,
                        const float* __restrict__ mvar,
                        float* __restrict__ out)
{
    __shared__ _Float16 wlds[DIN * DOUT];
    const int tid = threadIdx.x;
    {
        const int n = tid;
        const float inv = gamma[n] / sqrtf(mvar[n] + 1e-3f);
        const int t = n >> 4, nl0 = n & 15;
        #pragma unroll 8
        for (int k = 0; k < DIN; ++k) {
            const int q = k >> 5, qd = (k >> 3) & 3, j = k & 7;
            const int idx = (((((t << 2) + q) << 6) + (qd << 4) + nl0) << 3) + j;
            wlds[idx] = (_Float16)(W[k * DOUT + n] * inv);
        }
    }
    __syncthreads();

    const int lane = tid & 63, wv = tid >> 6;
    const int nl = lane & 15, quad = lane >> 4;

    float b2r[16];
    #pragma unroll
    for (int t = 0; t < 16; ++t) {
        const int c = (t << 4) + nl;
        const float inv = gamma[c] / sqrtf(mvar[c] + 1e-3f);
        b2r[t] = beta[c] - mmean[c] * inv;
    }

    for (int chunk = blockIdx.x; chunk < NCHUNKS; chunk += gridDim.x) {
        const int r0 = chunk * 64 + wv * 16;
        f16x8 af[4];
        const float* arow = A + (size_t)(r0 + nl) * DIN + (quad << 3);
        #pragma unroll
        for (int q = 0; q < 4; ++q) {
            const f32x4 vlo = *(const f32x4*)(arow + (q << 5));
            const f32x4 vhi = *(const f32x4*)(arow + (q << 5) + 4);
            f16x8 v;
            v[0] = (_Float16)vlo[0]; v[1] = (_Float16)vlo[1];
            v[2] = (_Float16)vlo[2]; v[3] = (_Float16)vlo[3];
            v[4] = (_Float16)vhi[0]; v[5] = (_Float16)vhi[1];
            v[6] = (_Float16)vhi[2]; v[7] = (_Float16)vhi[3];
            af[q] = v;
        }
        f32x4 acc[16];
        #pragma unroll
        for (int t = 0; t < 16; ++t) {
            f32x4 c = {0.f, 0.f, 0.f, 0.f};
            #pragma unroll
            for (int q = 0; q < 4; ++q) {
                const f16x8 bf = *(const f16x8*)&wlds[((((t << 2) + q) << 6) + lane) << 3];
                c = __builtin_amdgcn_mfma_f32_16x16x32_f16(af[q], bf, c, 0, 0, 0);
            }
            acc[t] = c;
        }
        const int rb = r0 + (quad << 2);
        #pragma unroll
        for (int t = 0; t < 16; ++t) {
            const int c = (t << 4) + nl;
            #pragma unroll
            for (int j = 0; j < 4; ++j) {
                const float p = priors[(size_t)(rb + j) * DOUT + c];
                acc[t][j] = (acc[t][j] + b2r[t]) * p;
            }
        }
        float tau[4] = {-3.0e38f, -3.0e38f, -3.0e38f, -3.0e38f};
        int   kp[4]  = {-1, -1, -1, -1};
        for (int it = 0; it < 64; ++it) {
            float S[4] = {0.f, 0.f, 0.f, 0.f};
            int   K[4] = {0, 0, 0, 0};
            #pragma unroll
            for (int t = 0; t < 16; ++t) {
                #pragma unroll
                for (int j = 0; j < 4; ++j) {
                    const float z = acc[t][j];
                    const bool b = z > tau[j];
                    S[j] += b ? z : 0.0f;
                    K[j] += b ? 1 : 0;
                }
            }
            #pragma unroll
            for (int j = 0; j < 4; ++j) {
                S[j] += SWZ_F(S[j], 0x041F); K[j] += SWZ_I(K[j], 0x041F);
                S[j] += SWZ_F(S[j], 0x081F); K[j] += SWZ_I(K[j], 0x081F);
                S[j] += SWZ_F(S[j], 0x101F); K[j] += SWZ_I(K[j], 0x101F);
                S[j] += SWZ_F(S[j], 0x201F); K[j] += SWZ_I(K[j], 0x201F);
            }
            bool conv = true;
            #pragma unroll
            for (int j = 0; j < 4; ++j) {
                tau[j] = (S[j] - 1.0f) * __builtin_amdgcn_rcpf((float)K[j]);
                conv = conv && (K[j] == kp[j]);
                kp[j] = K[j];
            }
            if (__all(conv)) break;
        }
        #pragma unroll
        for (int t = 0; t < 16; ++t) {
            const int c = (t << 4) + nl;
            #pragma unroll
            for (int j = 0; j < 4; ++j)
                out[(size_t)(rb + j) * DOUT + c] = fmaxf(acc[t][j] - tau[j], 0.0f);
        }
    }
}

extern "C" void kernel_launch(void* const* d_in, const int* in_sizes, int n_in,
                              void* d_out, int out_size, void* d_ws, size_t ws_size,
                              hipStream_t stream) {
    const float* inputs = (const float*)d_in[0];
    const float* priors = (const float*)d_in[1];
    const float* W      = (const float*)d_in[2];
    const float* gam    = (const float*)d_in[3];
    const float* bet    = (const float*)d_in[4];
    const float* mmean  = (const float*)d_in[5];
    const float* mvar   = (const float*)d_in[6];
    float* outp = (float*)d_out;
    (void)in_sizes; (void)n_in; (void)out_size;

    if (ws_size >= (size_t)WS_NEED) {
        _Float16* wq    = (_Float16*)d_ws;
        float*    b2tab = (float*)((char*)d_ws + DIN * DOUT * 2);
        hipLaunchKernelGGL(prep_kernel, dim3(16), dim3(256), 0, stream,
                           W, gam, bet, mmean, mvar, wq, b2tab);
        hipLaunchKernelGGL(attentive_main, dim3(NCHUNKS), dim3(256), 0, stream,
                           inputs, priors, wq, b2tab, outp);
    } else {
        hipLaunchKernelGGL(attentive_fallback, dim3(1024), dim3(256), 0, stream,
                           inputs, priors, W, gam, bet, mmean, mvar, outp);
    }
}

// Round 2
// 515.233 us; speedup vs baseline: 1.1923x; 1.0476x over previous
//
#include <hip/hip_runtime.h>

typedef _Float16 f16x8 __attribute__((ext_vector_type(8)));
typedef float    f32x4 __attribute__((ext_vector_type(4)));

#define NROWS   262144
#define DIN     128
#define DOUT    256
#define NCHUNKS (NROWS / 64)          // 4096 blocks, 64 rows each (4 waves x 16)
#define WS_NEED (DIN * DOUT * 2 + DOUT * 4)   // W' fp16 + b2 table

#define SWZ_F(x, pat) __int_as_float(__builtin_amdgcn_ds_swizzle(__float_as_int(x), (pat)))
#define SWZ_I(x, pat) __builtin_amdgcn_ds_swizzle((x), (pat))

// DPP cross-lane ops (VALU pipe, ~4cyc)
template<int CTRL>
__device__ __forceinline__ float dpp_addf(float x) {
    const int y = __builtin_amdgcn_mov_dpp(__float_as_int(x), CTRL, 0xF, 0xF, true);
    return x + __int_as_float(y);
}
template<int CTRL>
__device__ __forceinline__ float dpp_maxf(float x) {
    const int y = __builtin_amdgcn_mov_dpp(__float_as_int(x), CTRL, 0xF, 0xF, true);
    return fmaxf(x, __int_as_float(y));
}
#define DPP_XOR1 0xB1   // quad_perm [1,0,3,2]
#define DPP_XOR2 0x4E   // quad_perm [2,3,0,1]
#define DPP_HMIR 0x141  // row_half_mirror: swaps quads within 8-lane group

// ---------- prep: W' = W * gamma/rsqrt(var+eps) in fp16 B-frag order; b2 table ----------
__global__ void prep_kernel(const float* __restrict__ W,
                            const float* __restrict__ gamma,
                            const float* __restrict__ beta,
                            const float* __restrict__ mmean,
                            const float* __restrict__ mvar,
                            _Float16* __restrict__ wq,
                            float* __restrict__ b2tab)
{
    const int tid  = blockIdx.x * 256 + threadIdx.x;    // 0..4095 = (t, q, lane)
    const int t    = tid >> 8;
    const int q    = (tid >> 6) & 3;
    const int lane = tid & 63;
    const int n    = 16 * t + (lane & 15);
    const int k0   = 32 * q + 8 * (lane >> 4);
    const float inv = gamma[n] / sqrtf(mvar[n] + 1e-3f);
    f16x8 v;
    #pragma unroll
    for (int j = 0; j < 8; ++j)
        v[j] = (_Float16)(W[(k0 + j) * DOUT + n] * inv);
    *(f16x8*)(wq + (size_t)tid * 8) = v;               // frag half-index = ((t*4+q)*64+lane)*8+j
    if (blockIdx.x == 0) {
        const int c = threadIdx.x;
        const float invc = gamma[c] / sqrtf(mvar[c] + 1e-3f);
        b2tab[c] = beta[c] - mmean[c] * invc;
    }
}

// Michelot fixed point with warm start tau0 = rowmax - 1 (provably below tau*,
// monotone convergence to the exact fixed point; K>=1 always so kprev=0 is safe).
// zt = 8 x f32x4 (32 cols of one row per lane), row shared by the 8 lanes with
// equal (lane>>3). DPP tree-reduce over those 8.
__device__ __forceinline__ float michelot_ws(const f32x4* zt, float tau0) {
    float tau = tau0, kprev = 0.0f;
    for (int it = 0; it < 64; ++it) {
        float S = 0.0f, K = 0.0f;
        #pragma unroll
        for (int c = 0; c < 8; ++c) {
            #pragma unroll
            for (int j = 0; j < 4; ++j) {
                const float z = zt[c][j];
                const bool b = z > tau;
                S += b ? z : 0.0f;
                K += b ? 1.0f : 0.0f;
            }
        }
        S = dpp_addf<DPP_XOR1>(S); K = dpp_addf<DPP_XOR1>(K);
        S = dpp_addf<DPP_XOR2>(S); K = dpp_addf<DPP_XOR2>(K);
        S = dpp_addf<DPP_HMIR>(S); K = dpp_addf<DPP_HMIR>(K);
        tau = (S - 1.0f) * __builtin_amdgcn_rcpf(K);
        const bool conv = (K == kprev);
        kprev = K;
        if (__all(conv)) break;
    }
    return tau;
}

// ---------- main ----------
// Round-2 restructure: wq (64 KiB) is staged into LDS once per block via
// global_load_lds, so the GEMM B-fragments are ds_read_b128 with immediate
// offsets (no 16-round L2 latency chain). After a barrier the SAME 64 KiB is
// reused as 4x16KiB per-wave transpose buffers -> all 16 rows staged at once,
// acc dies right after the writes (no acc+zt register collision). LDS-bound
// at 2 blocks/CU, so registers are cheap: prefetch priors for BOTH passes and
// b2 during the GEMM.
__global__ __launch_bounds__(256, 2)
void attentive_main(const float* __restrict__ A,
                    const float* __restrict__ priors,
                    const _Float16* __restrict__ wq,
                    const float* __restrict__ b2tab,
                    float* __restrict__ out)
{
    __shared__ _Float16 wq_lds[DIN * DOUT];   // 64 KiB; post-GEMM: transpose buffers

    const int tid  = threadIdx.x;
    const int lane = tid & 63;
    const int wv   = tid >> 6;
    const int nl   = lane & 15;            // MFMA C-layout col-low / A row
    const int quad = lane >> 4;
    const int lo   = lane & 7;             // epilogue: col-group
    const int hi   = lane >> 3;            // epilogue: row within 8-row pass
    const int r0   = blockIdx.x * 64 + wv * 16;
    const int cb   = lo << 2;              // 16B offset within each 128B col-group

    // ---- stage W' into LDS: wave wv covers [wv*16KiB, +16KiB), 16 x 1KiB rounds ----
    {
        const char* gsrc = (const char*)wq + wv * 16384 + lane * 16;
        #pragma unroll
        for (int r = 0; r < 16; ++r) {
            __builtin_amdgcn_global_load_lds(
                (const __attribute__((address_space(1))) void*)(gsrc + r * 1024),
                (__attribute__((address_space(3))) void*)((char*)wq_lds + wv * 16384 + r * 1024),
                16, 0, 0);
        }
    }

    // ---- A fragments: A[m=nl][k = 32q + 8*quad + j], fp32 -> fp16 ----
    f16x8 af[4];
    {
        const float* arow = A + (size_t)(r0 + nl) * DIN + (quad << 3);
        #pragma unroll
        for (int q = 0; q < 4; ++q) {
            const f32x4 vlo = *(const f32x4*)(arow + (q << 5));
            const f32x4 vhi = *(const f32x4*)(arow + (q << 5) + 4);
            f16x8 v;
            v[0] = (_Float16)vlo[0]; v[1] = (_Float16)vlo[1];
            v[2] = (_Float16)vlo[2]; v[3] = (_Float16)vlo[3];
            v[4] = (_Float16)vhi[0]; v[5] = (_Float16)vhi[1];
            v[6] = (_Float16)vhi[2]; v[7] = (_Float16)vhi[3];
            af[q] = v;
        }
    }

    __syncthreads();   // staging (and A loads) drained; wq_lds valid for all waves

    // ---- prefetch priors (both passes) + b2 — latency hidden under the GEMM ----
    f32x4 pv0[8], pv1[8], b2v[8];
    {
        const float* pr0 = priors + (size_t)(r0 + hi) * DOUT;
        const float* pr1 = priors + (size_t)(r0 + 8 + hi) * DOUT;
        #pragma unroll
        for (int c = 0; c < 8; ++c) {
            pv0[c] = __builtin_nontemporal_load((const f32x4*)(pr0 + (c << 5) + cb));
            pv1[c] = __builtin_nontemporal_load((const f32x4*)(pr1 + (c << 5) + cb));
            b2v[c] = *(const f32x4*)(b2tab + (c << 5) + cb);
        }
    }

    // ---- GEMM from LDS: acc = A @ W'  (C-layout: col=16t+nl, row=4*quad+j) ----
    f32x4 acc[16];
    #pragma unroll
    for (int t = 0; t < 16; ++t) {
        f32x4 c = {0.f, 0.f, 0.f, 0.f};
        #pragma unroll
        for (int q = 0; q < 4; ++q) {
            const f16x8 bf = *(const f16x8*)&wq_lds[((((t << 2) + q) << 6) + lane) << 3];
            c = __builtin_amdgcn_mfma_f32_16x16x32_f16(af[q], bf, c, 0, 0, 0);
        }
        acc[t] = c;
    }

    __syncthreads();   // all waves done reading wq_lds; safe to overwrite

    // ---- transpose: ALL 16 rows into the wave's private 16 KiB; acc dies here ----
    float* buf = (float*)wq_lds + wv * 4096;
    #pragma unroll
    for (int t = 0; t < 16; ++t) {
        const int col = (t << 4) + nl;
        const int g = col >> 2, off = col & 3;
        #pragma unroll
        for (int j = 0; j < 4; ++j) {
            const int row = (quad << 2) + j;
            buf[row * 256 + (((g ^ (row & 7)) << 2) + off)] = acc[t][j];
        }
    }
    __asm__ volatile("s_waitcnt lgkmcnt(0)" ::: "memory");   // wave-private region: own writes drained

    // ---- pass 0: rows 0..7 ----
    {
        f32x4 zt0[8];
        #pragma unroll
        for (int c = 0; c < 8; ++c) {
            const int gp = ((c << 3) + lo) ^ hi;
            zt0[c] = *(const f32x4*)&buf[hi * 256 + (gp << 2)];
        }
        float m = -3.0e38f;
        #pragma unroll
        for (int c = 0; c < 8; ++c) {
            #pragma unroll
            for (int j = 0; j < 4; ++j) {
                const float z = (zt0[c][j] + b2v[c][j]) * pv0[c][j];
                zt0[c][j] = z;
                m = fmaxf(m, z);
            }
        }
        m = dpp_maxf<DPP_XOR1>(m);
        m = dpp_maxf<DPP_XOR2>(m);
        m = dpp_maxf<DPP_HMIR>(m);

        const float tau = michelot_ws(zt0, m - 1.0f);
        const int rg = r0 + hi;
        #pragma unroll
        for (int c = 0; c < 8; ++c) {
            f32x4 o;
            #pragma unroll
            for (int j = 0; j < 4; ++j)
                o[j] = fmaxf(zt0[c][j] - tau, 0.0f);
            __builtin_nontemporal_store(o, (f32x4*)(out + (size_t)rg * DOUT + (c << 5) + cb));
        }
    }

    // ---- pass 1: rows 8..15 ----
    {
        f32x4 zt1[8];
        #pragma unroll
        for (int c = 0; c < 8; ++c) {
            const int gp = ((c << 3) + lo) ^ hi;
            zt1[c] = *(const f32x4*)&buf[(8 + hi) * 256 + (gp << 2)];
        }
        float m1 = -3.0e38f;
        #pragma unroll
        for (int c = 0; c < 8; ++c) {
            #pragma unroll
            for (int j = 0; j < 4; ++j) {
                const float z = (zt1[c][j] + b2v[c][j]) * pv1[c][j];
                zt1[c][j] = z;
                m1 = fmaxf(m1, z);
            }
        }
        m1 = dpp_maxf<DPP_XOR1>(m1);
        m1 = dpp_maxf<DPP_XOR2>(m1);
        m1 = dpp_maxf<DPP_HMIR>(m1);

        const float tau1 = michelot_ws(zt1, m1 - 1.0f);
        const int rg1 = r0 + 8 + hi;
        #pragma unroll
        for (int c = 0; c < 8; ++c) {
            f32x4 o;
            #pragma unroll
            for (int j = 0; j < 4; ++j)
                o[j] = fmaxf(zt1[c][j] - tau1, 0.0f);
            __builtin_nontemporal_store(o, (f32x4*)(out + (size_t)rg1 * DOUT + (c << 5) + cb));
        }
    }
}

// ---------- fallback (round-1 kernel, proven correct) for tiny ws ----------
__global__ __launch_bounds__(256, 2)
void attentive_fallback(const float* __restrict__ A,
                        const float* __restrict__ priors,
                        const float* __restrict__ W,
                        const float* __restrict__ gamma,
                        const float* __restrict__ beta,
                        const float* __restrict__ mmean,
                        const float* __restrict__ mvar,
                        float* __restrict__ out)
{
    __shared__ _Float16 wlds[DIN * DOUT];
    const int tid = threadIdx.x;
    {
        const int n = tid;
        const float inv = gamma[n] / sqrtf(mvar[n] + 1e-3f);
        const int t = n >> 4, nl0 = n & 15;
        #pragma unroll 8
        for (int k = 0; k < DIN; ++k) {
            const int q = k >> 5, qd = (k >> 3) & 3, j = k & 7;
            const int idx = (((((t << 2) + q) << 6) + (qd << 4) + nl0) << 3) + j;
            wlds[idx] = (_Float16)(W[k * DOUT + n] * inv);
        }
    }
    __syncthreads();

    const int lane = tid & 63, wv = tid >> 6;
    const int nl = lane & 15, quad = lane >> 4;

    float b2r[16];
    #pragma unroll
    for (int t = 0; t < 16; ++t) {
        const int c = (t << 4) + nl;
        const float inv = gamma[c] / sqrtf(mvar[c] + 1e-3f);
        b2r[t] = beta[c] - mmean[c] * inv;
    }

    for (int chunk = blockIdx.x; chunk < NCHUNKS; chunk += gridDim.x) {
        const int r0 = chunk * 64 + wv * 16;
        f16x8 af[4];
        const float* arow = A + (size_t)(r0 + nl) * DIN + (quad << 3);
        #pragma unroll
        for (int q = 0; q < 4; ++q) {
            const f32x4 vlo = *(const f32x4*)(arow + (q << 5));
            const f32x4 vhi = *(const f32x4*)(arow + (q << 5) + 4);
            f16x8 v;
            v[0] = (_Float16)vlo[0]; v[1] = (_Float16)vlo[1];
            v[2] = (_Float16)vlo[2]; v[3] = (_Float16)vlo[3];
            v[4] = (_Float16)vhi[0]; v[5] = (_Float16)vhi[1];
            v[6] = (_Float16)vhi[2]; v[7] = (_Float16)vhi[3];
            af[q] = v;
        }
        f32x4 acc[16];
        #pragma unroll
        for (int t = 0; t < 16; ++t) {
            f32x4 c = {0.f, 0.f, 0.f, 0.f};
            #pragma unroll
            for (int q = 0; q < 4; ++q) {
                const f16x8 bf = *(const f16x8*)&wlds[((((t << 2) + q) << 6) + lane) << 3];
                c = __builtin_amdgcn_mfma_f32_16x16x32_f16(af[q], bf, c, 0, 0, 0);
            }
            acc[t] = c;
        }
        const int rb = r0 + (quad << 2);
        #pragma unroll
        for (int t = 0; t < 16; ++t) {
            const int c = (t << 4) + nl;
            #pragma unroll
            for (int j = 0; j < 4; ++j) {
                const float p = priors[(size_t)(rb + j) * DOUT + c];
                acc[t][j] = (acc[t][j] + b2r[t]) * p;
            }
        }
        float tau[4] = {-3.0e38f, -3.0e38f, -3.0e38f, -3.0e38f};
        int   kp[4]  = {-1, -1, -1, -1};
        for (int it = 0; it < 64; ++it) {
            float S[4] = {0.f, 0.f, 0.f, 0.f};
            int   K[4] = {0, 0, 0, 0};
            #pragma unroll
            for (int t = 0; t < 16; ++t) {
                #pragma unroll
                for (int j = 0; j < 4; ++j) {
                    const float z = acc[t][j];
                    const bool b = z > tau[j];
                    S[j] += b ? z : 0.0f;
                    K[j] += b ? 1 : 0;
                }
            }
            #pragma unroll
            for (int j = 0; j < 4; ++j) {
                S[j] += SWZ_F(S[j], 0x041F); K[j] += SWZ_I(K[j], 0x041F);
                S[j] += SWZ_F(S[j], 0x081F); K[j] += SWZ_I(K[j], 0x081F);
                S[j] += SWZ_F(S[j], 0x101F); K[j] += SWZ_I(K[j], 0x101F);
                S[j] += SWZ_F(S[j], 0x201F); K[j] += SWZ_I(K[j], 0x201F);
            }
            bool conv = true;
            #pragma unroll
            for (int j = 0; j < 4; ++j) {
                tau[j] = (S[j] - 1.0f) * __builtin_amdgcn_rcpf((float)K[j]);
                conv = conv && (K[j] == kp[j]);
                kp[j] = K[j];
            }
            if (__all(conv)) break;
        }
        #pragma unroll
        for (int t = 0; t < 16; ++t) {
            const int c = (t << 4) + nl;
            #pragma unroll
            for (int j = 0; j < 4; ++j)
                out[(size_t)(rb + j) * DOUT + c] = fmaxf(acc[t][j] - tau[j], 0.0f);
        }
    }
}

extern "C" void kernel_launch(void* const* d_in, const int* in_sizes, int n_in,
                              void* d_out, int out_size, void* d_ws, size_t ws_size,
                              hipStream_t stream) {
    const float* inputs = (const float*)d_in[0];
    const float* priors = (const float*)d_in[1];
    const float* W      = (const float*)d_in[2];
    const float* gam    = (const float*)d_in[3];
    const float* bet    = (const float*)d_in[4];
    const float* mmean  = (const float*)d_in[5];
    const float* mvar   = (const float*)d_in[6];
    float* outp = (float*)d_out;
    (void)in_sizes; (void)n_in; (void)out_size;

    if (ws_size >= (size_t)WS_NEED) {
        _Float16* wq    = (_Float16*)d_ws;
        float*    b2tab = (float*)((char*)d_ws + DIN * DOUT * 2);
        hipLaunchKernelGGL(prep_kernel, dim3(16), dim3(256), 0, stream,
                           W, gam, bet, mmean, mvar, wq, b2tab);
        hipLaunchKernelGGL(attentive_main, dim3(NCHUNKS), dim3(256), 0, stream,
                           inputs, priors, wq, b2tab, outp);
    } else {
        hipLaunchKernelGGL(attentive_fallback, dim3(1024), dim3(256), 0, stream,
                           inputs, priors, W, gam, bet, mmean, mvar, outp);
    }
}